// Round 9
// baseline (933.073 us; speedup 1.0000x reference)
//
#include <hip/hip_runtime.h>

// Problem constants: Bq=128, Bk=128, Nk=256, C=1024, H=16, hd=64, scale=0.125, eps=1e-5.

typedef unsigned short ushort_t;
typedef __bf16 bf16x8 __attribute__((ext_vector_type(8)));
typedef float f32x4 __attribute__((ext_vector_type(4)));

#define AS1 __attribute__((address_space(1)))
#define AS3 __attribute__((address_space(3)))

__device__ __forceinline__ void gload_lds16(const void* g, void* l) {
  __builtin_amdgcn_global_load_lds((const AS1 unsigned int*)g, (AS3 unsigned int*)l, 16, 0, 0);
}

__device__ __forceinline__ ushort_t f2bf(float f) {
  unsigned u = __float_as_uint(f);
  unsigned r = u + 0x7FFFu + ((u >> 16) & 1u);
  return (ushort_t)(r >> 16);
}

// ---------------------------------------------------------------------------
// K0: fp32 -> bf16 convert (for Wq / Wk)
// ---------------------------------------------------------------------------
__global__ __launch_bounds__(256) void cvt_bf16_kernel(const float* __restrict__ src,
                                                       ushort_t* __restrict__ dst, int n4) {
  int i = blockIdx.x * 256 + threadIdx.x;
  if (i < n4) {
    float4 v = ((const float4*)src)[i];
    ushort4 o;
    o.x = f2bf(v.x); o.y = f2bf(v.y); o.z = f2bf(v.z); o.w = f2bf(v.w);
    ((ushort4*)dst)[i] = o;
  }
}

// ---------------------------------------------------------------------------
// K1: LayerNorm rows -> bf16.  rows 0..32767: kx -> kln; rows 32768+: qx -> qln
// ---------------------------------------------------------------------------
__global__ __launch_bounds__(256) void ln_kernel(const float* __restrict__ kx,
                                                 const float* __restrict__ qx,
                                                 const float* __restrict__ gk,
                                                 const float* __restrict__ bk,
                                                 const float* __restrict__ gq,
                                                 const float* __restrict__ bq,
                                                 ushort_t* __restrict__ kln,
                                                 ushort_t* __restrict__ qln) {
  int row = blockIdx.x;
  const float* src; ushort_t* dst; const float* g; const float* bb;
  if (row < 32768) {
    src = kx + (size_t)row * 1024; dst = kln + (size_t)row * 1024; g = gk; bb = bk;
  } else {
    int r = row - 32768;
    src = qx + (size_t)r * 1024; dst = qln + (size_t)r * 1024; g = gq; bb = bq;
  }
  int tid = threadIdx.x;
  float4 v = ((const float4*)src)[tid];
  float s  = v.x + v.y + v.z + v.w;
  float s2 = v.x*v.x + v.y*v.y + v.z*v.z + v.w*v.w;
  #pragma unroll
  for (int off = 1; off < 64; off <<= 1) {
    s  += __shfl_xor(s, off);
    s2 += __shfl_xor(s2, off);
  }
  __shared__ float red[8];
  int wid = tid >> 6, lane = tid & 63;
  if (lane == 0) { red[wid] = s; red[4 + wid] = s2; }
  __syncthreads();
  s  = red[0] + red[1] + red[2] + red[3];
  s2 = red[4] + red[5] + red[6] + red[7];
  float mean = s * (1.0f / 1024.0f);
  float var  = s2 * (1.0f / 1024.0f) - mean * mean;
  float rstd = rsqrtf(var + 1e-5f);
  float4 gg = ((const float4*)g)[tid];
  float4 b4 = ((const float4*)bb)[tid];
  ushort4 o;
  o.x = f2bf((v.x - mean) * rstd * gg.x + b4.x);
  o.y = f2bf((v.y - mean) * rstd * gg.y + b4.y);
  o.z = f2bf((v.z - mean) * rstd * gg.z + b4.z);
  o.w = f2bf((v.w - mean) * rstd * gg.w + b4.w);
  ((ushort4*)dst)[tid] = o;
}

// ---------------------------------------------------------------------------
// K3: merged GEMM kernel, 512 blocks x 512 thr (8 waves), 2 blocks/CU.
// Main: 256x256-tile K-projection, BK=32, TWO LDS buffers (64 KiB),
//   counted-vmcnt pipeline: stage(u+2) issued while computing u; vmcnt(4)
//   waits only for tile u+1; per-wave lgkmcnt(0) before the re-stage barrier
//   protects the write-after-read on buf[u&1].  Packed-fragment epilogue.
// Coda: each block computes ONE 16x16 Q-projection tile (8m x 64n = 512)
//   with fragments loaded directly from L2-resident qln/Wqb. No extra dispatch.
// ---------------------------------------------------------------------------
__global__ __launch_bounds__(512, 4) void gemm256_kernel(const ushort_t* __restrict__ A,
                                                         const ushort_t* __restrict__ Bt,
                                                         ushort_t* __restrict__ Cpk,
                                                         const ushort_t* __restrict__ qA,
                                                         const ushort_t* __restrict__ qB,
                                                         ushort_t* __restrict__ qC,
                                                         int M, int N) {
  __shared__ ushort_t lds[2][2][256 * 32];

  const int tid = threadIdx.x, lane = tid & 63, wid = tid >> 6;
  const int g = lane >> 4, rr = lane & 15;
  const int wr = wid >> 2, wc = wid & 3;

  const int Mt = M >> 8, Nt = N >> 8;
  const int nwg = Mt * Nt;
  const int qq = nwg >> 3, r8 = nwg & 7;
  const int xcd = blockIdx.x & 7, idx = blockIdx.x >> 3;
  const int wg = (xcd < r8 ? xcd * (qq + 1) : r8 * (qq + 1) + (xcd - r8) * qq) + idx;
  const int mt = wg / Nt, nt = wg - mt * Nt;
  const size_t m0 = (size_t)mt << 8, n0 = (size_t)nt << 8;

  // staging: lane l -> row s_r = l>>2, granule pre-swizzled (r7-verified form)
  const int s_r  = lane >> 2;
  const int s_gr = (lane & 3) ^ (s_r & 3);

  const ushort_t* Abase = A  + m0 * 1024;
  const ushort_t* Bbase = Bt + n0 * 1024;

  f32x4 acc[8][4];
  #pragma unroll
  for (int i = 0; i < 8; ++i)
    #pragma unroll
    for (int j = 0; j < 4; ++j) acc[i][j] = (f32x4){0.f, 0.f, 0.f, 0.f};

  auto stage = [&](int kt) {   // 4 loads/thread: A,A,B,B (FIFO order matters for vmcnt)
    const int k0 = kt << 5;
    ushort_t* dstA = &lds[kt & 1][0][0];
    ushort_t* dstB = &lds[kt & 1][1][0];
    #pragma unroll
    for (int it = 0; it < 2; ++it) {
      int ci = (wid << 1) | it;
      int r  = (ci << 4) + s_r;
      gload_lds16(Abase + (size_t)r * 1024 + k0 + (s_gr << 3), dstA + (ci << 9));
    }
    #pragma unroll
    for (int it = 0; it < 2; ++it) {
      int ci = (wid << 1) | it;
      int r  = (ci << 4) + s_r;
      gload_lds16(Bbase + (size_t)r * 1024 + k0 + (s_gr << 3), dstB + (ci << 9));
    }
  };

  // prologue: tiles 0 and 1 in flight; retire tile 0.
  stage(0); stage(1);
  asm volatile("s_waitcnt vmcnt(4)" ::: "memory");
  __builtin_amdgcn_s_barrier();

  const int rsw = rr & 3;

  #pragma unroll 1
  for (int u = 0; u < 30; ++u) {
    const ushort_t* as = &lds[u & 1][0][0];
    const ushort_t* bs = &lds[u & 1][1][0];
    bf16x8 af[8], bf[4];
    #pragma unroll
    for (int i = 0; i < 8; ++i) {
      int r = (wr << 7) + (i << 4) + rr;
      af[i] = *(const bf16x8*)&as[(r << 5) + ((g ^ rsw) << 3)];
    }
    #pragma unroll
    for (int j = 0; j < 4; ++j) {
      int r = (wc << 6) + (j << 4) + rr;
      bf[j] = *(const bf16x8*)&bs[(r << 5) + ((g ^ rsw) << 3)];
    }
    // all frags resident before anyone may overwrite buf[u&1]
    asm volatile("s_waitcnt lgkmcnt(0)" ::: "memory");
    __builtin_amdgcn_s_barrier();
    stage(u + 2);                        // overwrites buf[u&1]; safe now
    __builtin_amdgcn_s_setprio(1);
    #pragma unroll
    for (int i = 0; i < 8; ++i)
      #pragma unroll
      for (int j = 0; j < 4; ++j)
        acc[i][j] = __builtin_amdgcn_mfma_f32_16x16x32_bf16(af[i], bf[j], acc[i][j], 0, 0, 0);
    __builtin_amdgcn_s_setprio(0);
    asm volatile("s_waitcnt vmcnt(4)" ::: "memory");   // tile u+1 landed
    __builtin_amdgcn_s_barrier();
  }

  // u = 30: no more staging; drain tile 31 fully.
  {
    const ushort_t* as = &lds[0][0][0];
    const ushort_t* bs = &lds[0][1][0];
    bf16x8 af[8], bf[4];
    #pragma unroll
    for (int i = 0; i < 8; ++i) {
      int r = (wr << 7) + (i << 4) + rr;
      af[i] = *(const bf16x8*)&as[(r << 5) + ((g ^ rsw) << 3)];
    }
    #pragma unroll
    for (int j = 0; j < 4; ++j) {
      int r = (wc << 6) + (j << 4) + rr;
      bf[j] = *(const bf16x8*)&bs[(r << 5) + ((g ^ rsw) << 3)];
    }
    #pragma unroll
    for (int i = 0; i < 8; ++i)
      #pragma unroll
      for (int j = 0; j < 4; ++j)
        acc[i][j] = __builtin_amdgcn_mfma_f32_16x16x32_bf16(af[i], bf[j], acc[i][j], 0, 0, 0);
    asm volatile("s_waitcnt vmcnt(0)" ::: "memory");
    __builtin_amdgcn_s_barrier();
  }
  // u = 31
  {
    const ushort_t* as = &lds[1][0][0];
    const ushort_t* bs = &lds[1][1][0];
    bf16x8 af[8], bf[4];
    #pragma unroll
    for (int i = 0; i < 8; ++i) {
      int r = (wr << 7) + (i << 4) + rr;
      af[i] = *(const bf16x8*)&as[(r << 5) + ((g ^ rsw) << 3)];
    }
    #pragma unroll
    for (int j = 0; j < 4; ++j) {
      int r = (wc << 6) + (j << 4) + rr;
      bf[j] = *(const bf16x8*)&bs[(r << 5) + ((g ^ rsw) << 3)];
    }
    #pragma unroll
    for (int i = 0; i < 8; ++i)
      #pragma unroll
      for (int j = 0; j < 4; ++j)
        acc[i][j] = __builtin_amdgcn_mfma_f32_16x16x32_bf16(af[i], bf[j], acc[i][j], 0, 0, 0);
  }

  // packed epilogue: idx = ((kb*16+h)*16+t)*1024 + half*512 + g*128 + r16*8 + e
  #pragma unroll
  for (int i = 0; i < 8; ++i)
    #pragma unroll
    for (int j = 0; j < 4; ++j)
      #pragma unroll
      for (int rg = 0; rg < 4; ++rg) {
        size_t row = m0 + (wr << 7) + (i << 4) + (g << 2) + rg;
        size_t col = n0 + (wc << 6) + (j << 4) + rr;
        int kb = (int)(row >> 8), t = (int)((row >> 4) & 15), r16 = (int)(row & 15);
        int h = (int)(col >> 6), ch = (int)(col & 63);
        size_t idx = ((((size_t)kb * 16 + h) * 16 + t) << 10)
                   + ((ch >> 5) << 9) + (((ch >> 3) & 3) << 7) + (r16 << 3) + (ch & 7);
        Cpk[idx] = f2bf(acc[i][j][rg]);
      }

  // ---------------- Q-projection coda: one 16x16 tile per block ----------------
  // block -> (mq = wg>>6, nq = wg&63); output rows 16mq.., cols 16nq..
  {
    const int mq = wg >> 6, nq = wg & 63;
    const ushort_t* qa = qA + (size_t)(mq * 16 + rr) * 1024 + g * 8;
    const ushort_t* qb = qB + (size_t)(nq * 16 + rr) * 1024 + g * 8;
    f32x4 qacc = (f32x4){0.f, 0.f, 0.f, 0.f};
    #pragma unroll
    for (int kk = 0; kk < 32; ++kk) {
      bf16x8 a = *(const bf16x8*)(qa + kk * 32);
      bf16x8 b = *(const bf16x8*)(qb + kk * 32);
      qacc = __builtin_amdgcn_mfma_f32_16x16x32_bf16(a, b, qacc, 0, 0, 0);
    }
    #pragma unroll
    for (int rg = 0; rg < 4; ++rg)
      qC[(size_t)(mq * 16 + (g << 2) + rg) * 1024 + nq * 16 + rr] = f2bf(qacc[rg]);
  }
}

// ---------------------------------------------------------------------------
// K4a: scores kernel (unchanged: packed K loads, static indexing).
// ---------------------------------------------------------------------------
__global__ __launch_bounds__(256, 3) void scores_kernel(const ushort_t* __restrict__ qp,   // [128][1024]
                                                        const ushort_t* __restrict__ kpk,  // packed
                                                        ushort_t* __restrict__ wbuf) {     // [128][128][256]
  __shared__ float pbuf[2][16][258];

  const int tid = threadIdx.x, lane = tid & 63, wid = tid >> 6;
  const int g = lane >> 4, rr = lane & 15;

  const int b = blockIdx.x;
  const int wg = (b & 7) * 128 + (b >> 3);
  const int kb = wg >> 3;
  const int q0 = (wg & 7) << 4;

  const int hs = wid;

  float w_acc[16][4];
  #pragma unroll
  for (int t = 0; t < 16; ++t)
    #pragma unroll
    for (int r = 0; r < 4; ++r) w_acc[t][r] = 0.f;

  const ushort_t* qrow = qp + (size_t)(q0 + rr) * 1024;
  const ushort_t* kbb  = kpk + ((size_t)kb * 16) * 16384 + g * 128 + rr * 8;

  for (int hp = 0; hp < 4; ++hp) {
    const int h = hp * 4 + hs;
    const int co = h * 64 + g * 8;
    bf16x8 aq0 = *(const bf16x8*)(qrow + co);
    bf16x8 aq1 = *(const bf16x8*)(qrow + co + 32);
    const ushort_t* hb = kbb + (size_t)h * 16384;
    f32x4 s[16];
    #pragma unroll
    for (int t = 0; t < 16; ++t) {
      bf16x8 b0 = *(const bf16x8*)(hb + t * 1024);
      bf16x8 b1 = *(const bf16x8*)(hb + t * 1024 + 512);
      f32x4 a = (f32x4){0.f, 0.f, 0.f, 0.f};
      a = __builtin_amdgcn_mfma_f32_16x16x32_bf16(aq0, b0, a, 0, 0, 0);
      a = __builtin_amdgcn_mfma_f32_16x16x32_bf16(aq1, b1, a, 0, 0, 0);
      s[t] = a;
    }
    #pragma unroll
    for (int r = 0; r < 4; ++r) {
      float mx = s[0][r];
      #pragma unroll
      for (int t = 1; t < 16; ++t) mx = fmaxf(mx, s[t][r]);
      mx = fmaxf(mx, __shfl_xor(mx, 1));
      mx = fmaxf(mx, __shfl_xor(mx, 2));
      mx = fmaxf(mx, __shfl_xor(mx, 4));
      mx = fmaxf(mx, __shfl_xor(mx, 8));
      float sum = 0.f;
      float e[16];
      #pragma unroll
      for (int t = 0; t < 16; ++t) {
        e[t] = __expf((s[t][r] - mx) * 0.125f);
        sum += e[t];
      }
      sum += __shfl_xor(sum, 1);
      sum += __shfl_xor(sum, 2);
      sum += __shfl_xor(sum, 4);
      sum += __shfl_xor(sum, 8);
      float inv = 1.0f / sum;
      #pragma unroll
      for (int t = 0; t < 16; ++t) w_acc[t][r] += e[t] * inv;
    }
  }

  __syncthreads();
  if (hs >= 2) {
    #pragma unroll
    for (int t = 0; t < 16; ++t)
      #pragma unroll
      for (int r = 0; r < 4; ++r)
        pbuf[hs - 2][(g << 2) + r][t * 16 + rr] = w_acc[t][r];
  }
  __syncthreads();
  if (hs < 2) {
    #pragma unroll
    for (int t = 0; t < 16; ++t)
      #pragma unroll
      for (int r = 0; r < 4; ++r)
        w_acc[t][r] += pbuf[hs][(g << 2) + r][t * 16 + rr];
    if (hs == 1) {
      #pragma unroll
      for (int t = 0; t < 16; ++t)
        #pragma unroll
        for (int r = 0; r < 4; ++r)
          pbuf[1][(g << 2) + r][t * 16 + rr] = w_acc[t][r];
    }
  }
  __syncthreads();
  if (hs == 0) {
    ushort_t* wb = wbuf + (size_t)kb * 32768;
    #pragma unroll
    for (int t = 0; t < 16; ++t)
      #pragma unroll
      for (int r = 0; r < 4; ++r) {
        float v = w_acc[t][r] + pbuf[1][(g << 2) + r][t * 16 + rr];
        wb[(size_t)(q0 + (g << 2) + r) * 256 + t * 16 + rr] = f2bf(v);
      }
  }
}

// ---------------------------------------------------------------------------
// K4b: PV kernel (unchanged).
// ---------------------------------------------------------------------------
__global__ __launch_bounds__(256, 4) void pv_kernel(const ushort_t* __restrict__ wbuf, // [128][128][256]
                                                    const float* __restrict__ kx,      // [32768][1024]
                                                    float* __restrict__ xout) {        // [128][128][1024]
  const int tid = threadIdx.x, lane = tid & 63, wid = tid >> 6;
  const int g = lane >> 4, rr = lane & 15;

  const int b = blockIdx.x;
  const int wg = (b & 7) * 128 + (b >> 3);
  const int kb = wg >> 3;
  const int c0 = (wg & 7) * 128;

  const int wr = wid >> 1, wc = wid & 1;

  f32x4 acc[4][4];
  #pragma unroll
  for (int i = 0; i < 4; ++i)
    #pragma unroll
    for (int j = 0; j < 4; ++j) acc[i][j] = (f32x4){0.f, 0.f, 0.f, 0.f};

  const ushort_t* wb = wbuf + (size_t)kb * 32768;
  const float* kxb = kx + (size_t)kb * 256 * 1024;

  for (int nc = 0; nc < 8; ++nc) {
    const int n0 = nc * 32 + g * 8;
    bf16x8 af[4];
    #pragma unroll
    for (int i = 0; i < 4; ++i) {
      int q = (wr << 6) + (i << 4) + rr;
      af[i] = *(const bf16x8*)(wb + (size_t)q * 256 + n0);
    }
    #pragma unroll
    for (int j = 0; j < 4; ++j) {
      int c = c0 + (wc << 6) + (j << 4) + rr;
      const float* src = kxb + (size_t)n0 * 1024 + c;
      float f[8];
      #pragma unroll
      for (int jj = 0; jj < 8; ++jj) f[jj] = src[(size_t)jj * 1024];
      bf16x8 bb;
      #pragma unroll
      for (int jj = 0; jj < 8; ++jj) bb[jj] = (__bf16)f[jj];
      #pragma unroll
      for (int i = 0; i < 4; ++i)
        acc[i][j] = __builtin_amdgcn_mfma_f32_16x16x32_bf16(af[i], bb, acc[i][j], 0, 0, 0);
    }
  }

  #pragma unroll
  for (int i = 0; i < 4; ++i)
    #pragma unroll
    for (int j = 0; j < 4; ++j)
      #pragma unroll
      for (int rg = 0; rg < 4; ++rg) {
        int q = (wr << 6) + (i << 4) + (g << 2) + rg;
        int c = c0 + (wc << 6) + (j << 4) + rr;
        xout[((size_t)q * 128 + kb) * 1024 + c] = acc[i][j][rg];
      }
}

// ---------------------------------------------------------------------------
// launcher
// ---------------------------------------------------------------------------
extern "C" void kernel_launch(void* const* d_in, const int* in_sizes, int n_in,
                              void* d_out, int out_size, void* d_ws, size_t ws_size,
                              hipStream_t stream) {
  const float* qx = (const float*)d_in[0];
  const float* kx = (const float*)d_in[1];
  const float* gq = (const float*)d_in[2];
  const float* bq = (const float*)d_in[3];
  const float* gk = (const float*)d_in[4];
  const float* bk = (const float*)d_in[5];
  const float* Wq = (const float*)d_in[6];
  const float* Wk = (const float*)d_in[7];

  char* ws = (char*)d_ws;
  // ws layout (total 72.25 MiB):
  //   [0, 64M)            kkp   : PACKED K-projection bf16 (live: gemm256 -> scores)
  //   [64M, 64M+256K)     qproj : Q-projection bf16 [128][1024]    (live: gemm256 -> scores)
  //   [64M+256K, +8M)     wbuf  : head-summed weights bf16 [128][128][256] (live: scores -> pv)
  //     aliased inside wbuf (dead before scores runs):
  //       qln  @wbuf+0     [128][1024] bf16   (live: ln -> gemm256)
  //       Wqb  @wbuf+256K  [1024][1024] bf16  (live: cvt -> gemm256)
  //       Wkb  @wbuf+2.25M [1024][1024] bf16  (live: cvt -> gemm256)
  ushort_t* kkp   = (ushort_t*)(ws);
  ushort_t* qproj = (ushort_t*)(ws + 67108864);
  ushort_t* wbuf  = (ushort_t*)(ws + 67371008);
  ushort_t* qln   = (ushort_t*)(ws + 67371008);
  ushort_t* Wqb   = (ushort_t*)(ws + 67371008 + 262144);
  ushort_t* Wkb   = (ushort_t*)(ws + 67371008 + 2359296);
  // kln (bf16, 64 MiB) lives in d_out; dead after gemm256, overwritten by pv.
  ushort_t* kln  = (ushort_t*)d_out;
  float*    xout = (float*)d_out;

  cvt_bf16_kernel<<<1024, 256, 0, stream>>>(Wq, Wqb, 262144);
  cvt_bf16_kernel<<<1024, 256, 0, stream>>>(Wk, Wkb, 262144);
  ln_kernel<<<32896, 256, 0, stream>>>(kx, qx, gk, bk, gq, bq, kln, qln);
  gemm256_kernel<<<512, 512, 0, stream>>>(kln, Wkb, kkp, qln, Wqb, qproj, 32768, 1024);
  scores_kernel<<<1024, 256, 0, stream>>>(qproj, kkp, wbuf);
  pv_kernel<<<1024, 256, 0, stream>>>(wbuf, kx, xout);
}

// Round 10
// 287.527 us; speedup vs baseline: 3.2452x; 3.2452x over previous
//
#include <hip/hip_runtime.h>

// Problem constants: Bq=128, Bk=128, Nk=256, C=1024, H=16, hd=64, scale=0.125, eps=1e-5.

typedef unsigned short ushort_t;
typedef __bf16 bf16x8 __attribute__((ext_vector_type(8)));
typedef float f32x4 __attribute__((ext_vector_type(4)));

#define AS1 __attribute__((address_space(1)))
#define AS3 __attribute__((address_space(3)))

__device__ __forceinline__ void gload_lds16(const void* g, void* l) {
  __builtin_amdgcn_global_load_lds((const AS1 unsigned int*)g, (AS3 unsigned int*)l, 16, 0, 0);
}

__device__ __forceinline__ ushort_t f2bf(float f) {
  unsigned u = __float_as_uint(f);
  unsigned r = u + 0x7FFFu + ((u >> 16) & 1u);
  return (ushort_t)(r >> 16);
}

// ---------------------------------------------------------------------------
// K0: fp32 -> bf16 convert (for Wq / Wk)
// ---------------------------------------------------------------------------
__global__ __launch_bounds__(256) void cvt_bf16_kernel(const float* __restrict__ src,
                                                       ushort_t* __restrict__ dst, int n4) {
  int i = blockIdx.x * 256 + threadIdx.x;
  if (i < n4) {
    float4 v = ((const float4*)src)[i];
    ushort4 o;
    o.x = f2bf(v.x); o.y = f2bf(v.y); o.z = f2bf(v.z); o.w = f2bf(v.w);
    ((ushort4*)dst)[i] = o;
  }
}

// ---------------------------------------------------------------------------
// K1: LayerNorm rows -> bf16.  rows 0..32767: kx -> kln; rows 32768+: qx -> qln
// ---------------------------------------------------------------------------
__global__ __launch_bounds__(256) void ln_kernel(const float* __restrict__ kx,
                                                 const float* __restrict__ qx,
                                                 const float* __restrict__ gk,
                                                 const float* __restrict__ bk,
                                                 const float* __restrict__ gq,
                                                 const float* __restrict__ bq,
                                                 ushort_t* __restrict__ kln,
                                                 ushort_t* __restrict__ qln) {
  int row = blockIdx.x;
  const float* src; ushort_t* dst; const float* g; const float* bb;
  if (row < 32768) {
    src = kx + (size_t)row * 1024; dst = kln + (size_t)row * 1024; g = gk; bb = bk;
  } else {
    int r = row - 32768;
    src = qx + (size_t)r * 1024; dst = qln + (size_t)r * 1024; g = gq; bb = bq;
  }
  int tid = threadIdx.x;
  float4 v = ((const float4*)src)[tid];
  float s  = v.x + v.y + v.z + v.w;
  float s2 = v.x*v.x + v.y*v.y + v.z*v.z + v.w*v.w;
  #pragma unroll
  for (int off = 1; off < 64; off <<= 1) {
    s  += __shfl_xor(s, off);
    s2 += __shfl_xor(s2, off);
  }
  __shared__ float red[8];
  int wid = tid >> 6, lane = tid & 63;
  if (lane == 0) { red[wid] = s; red[4 + wid] = s2; }
  __syncthreads();
  s  = red[0] + red[1] + red[2] + red[3];
  s2 = red[4] + red[5] + red[6] + red[7];
  float mean = s * (1.0f / 1024.0f);
  float var  = s2 * (1.0f / 1024.0f) - mean * mean;
  float rstd = rsqrtf(var + 1e-5f);
  float4 gg = ((const float4*)g)[tid];
  float4 b4 = ((const float4*)bb)[tid];
  ushort4 o;
  o.x = f2bf((v.x - mean) * rstd * gg.x + b4.x);
  o.y = f2bf((v.y - mean) * rstd * gg.y + b4.y);
  o.z = f2bf((v.z - mean) * rstd * gg.z + b4.z);
  o.w = f2bf((v.w - mean) * rstd * gg.w + b4.w);
  ((ushort4*)dst)[tid] = o;
}

// ---------------------------------------------------------------------------
// K3: merged GEMM kernel, 512 blocks x 512 thr (8 waves), 2 blocks/CU (LDS-limited).
// Main: 256x256-tile K-projection, BK=32, TWO LDS buffers (64 KiB),
//   counted-vmcnt pipeline: stage(u+2) issued while computing u; vmcnt(4)
//   waits only for tile u+1; per-wave lgkmcnt(0) before the re-stage barrier
//   protects the write-after-read on buf[u&1].  Packed-fragment epilogue.
// Coda: each block computes ONE 16x16 Q-projection tile (8m x 64n = 512).
// NOTE launch bound (512,2): cap 256 VGPR. (512,4) caused a 30x spill (r9).
// ---------------------------------------------------------------------------
__global__ __launch_bounds__(512, 2) void gemm256_kernel(const ushort_t* __restrict__ A,
                                                         const ushort_t* __restrict__ Bt,
                                                         ushort_t* __restrict__ Cpk,
                                                         const ushort_t* __restrict__ qA,
                                                         const ushort_t* __restrict__ qB,
                                                         ushort_t* __restrict__ qC,
                                                         int M, int N) {
  __shared__ ushort_t lds[2][2][256 * 32];

  const int tid = threadIdx.x, lane = tid & 63, wid = tid >> 6;
  const int g = lane >> 4, rr = lane & 15;
  const int wr = wid >> 2, wc = wid & 3;

  const int Mt = M >> 8, Nt = N >> 8;
  const int nwg = Mt * Nt;
  const int qq = nwg >> 3, r8 = nwg & 7;
  const int xcd = blockIdx.x & 7, idx = blockIdx.x >> 3;
  const int wg = (xcd < r8 ? xcd * (qq + 1) : r8 * (qq + 1) + (xcd - r8) * qq) + idx;
  const int mt = wg / Nt, nt = wg - mt * Nt;
  const size_t m0 = (size_t)mt << 8, n0 = (size_t)nt << 8;

  const int s_r  = lane >> 2;
  const int s_gr = (lane & 3) ^ (s_r & 3);

  const ushort_t* Abase = A  + m0 * 1024;
  const ushort_t* Bbase = Bt + n0 * 1024;

  f32x4 acc[8][4];
  #pragma unroll
  for (int i = 0; i < 8; ++i)
    #pragma unroll
    for (int j = 0; j < 4; ++j) acc[i][j] = (f32x4){0.f, 0.f, 0.f, 0.f};

  auto stage = [&](int kt) {   // 4 loads/thread: A,A,B,B
    const int k0 = kt << 5;
    ushort_t* dstA = &lds[kt & 1][0][0];
    ushort_t* dstB = &lds[kt & 1][1][0];
    #pragma unroll
    for (int it = 0; it < 2; ++it) {
      int ci = (wid << 1) | it;
      int r  = (ci << 4) + s_r;
      gload_lds16(Abase + (size_t)r * 1024 + k0 + (s_gr << 3), dstA + (ci << 9));
    }
    #pragma unroll
    for (int it = 0; it < 2; ++it) {
      int ci = (wid << 1) | it;
      int r  = (ci << 4) + s_r;
      gload_lds16(Bbase + (size_t)r * 1024 + k0 + (s_gr << 3), dstB + (ci << 9));
    }
  };

  stage(0); stage(1);
  asm volatile("s_waitcnt vmcnt(4)" ::: "memory");
  __builtin_amdgcn_s_barrier();

  const int rsw = rr & 3;

  #pragma unroll 1
  for (int u = 0; u < 30; ++u) {
    const ushort_t* as = &lds[u & 1][0][0];
    const ushort_t* bs = &lds[u & 1][1][0];
    bf16x8 af[8], bf[4];
    #pragma unroll
    for (int i = 0; i < 8; ++i) {
      int r = (wr << 7) + (i << 4) + rr;
      af[i] = *(const bf16x8*)&as[(r << 5) + ((g ^ rsw) << 3)];
    }
    #pragma unroll
    for (int j = 0; j < 4; ++j) {
      int r = (wc << 6) + (j << 4) + rr;
      bf[j] = *(const bf16x8*)&bs[(r << 5) + ((g ^ rsw) << 3)];
    }
    asm volatile("s_waitcnt lgkmcnt(0)" ::: "memory");
    __builtin_amdgcn_s_barrier();
    stage(u + 2);
    __builtin_amdgcn_s_setprio(1);
    #pragma unroll
    for (int i = 0; i < 8; ++i)
      #pragma unroll
      for (int j = 0; j < 4; ++j)
        acc[i][j] = __builtin_amdgcn_mfma_f32_16x16x32_bf16(af[i], bf[j], acc[i][j], 0, 0, 0);
    __builtin_amdgcn_s_setprio(0);
    asm volatile("s_waitcnt vmcnt(4)" ::: "memory");
    __builtin_amdgcn_s_barrier();
  }

  // u = 30
  {
    const ushort_t* as = &lds[0][0][0];
    const ushort_t* bs = &lds[0][1][0];
    bf16x8 af[8], bf[4];
    #pragma unroll
    for (int i = 0; i < 8; ++i) {
      int r = (wr << 7) + (i << 4) + rr;
      af[i] = *(const bf16x8*)&as[(r << 5) + ((g ^ rsw) << 3)];
    }
    #pragma unroll
    for (int j = 0; j < 4; ++j) {
      int r = (wc << 6) + (j << 4) + rr;
      bf[j] = *(const bf16x8*)&bs[(r << 5) + ((g ^ rsw) << 3)];
    }
    #pragma unroll
    for (int i = 0; i < 8; ++i)
      #pragma unroll
      for (int j = 0; j < 4; ++j)
        acc[i][j] = __builtin_amdgcn_mfma_f32_16x16x32_bf16(af[i], bf[j], acc[i][j], 0, 0, 0);
    asm volatile("s_waitcnt vmcnt(0)" ::: "memory");
    __builtin_amdgcn_s_barrier();
  }
  // u = 31
  {
    const ushort_t* as = &lds[1][0][0];
    const ushort_t* bs = &lds[1][1][0];
    bf16x8 af[8], bf[4];
    #pragma unroll
    for (int i = 0; i < 8; ++i) {
      int r = (wr << 7) + (i << 4) + rr;
      af[i] = *(const bf16x8*)&as[(r << 5) + ((g ^ rsw) << 3)];
    }
    #pragma unroll
    for (int j = 0; j < 4; ++j) {
      int r = (wc << 6) + (j << 4) + rr;
      bf[j] = *(const bf16x8*)&bs[(r << 5) + ((g ^ rsw) << 3)];
    }
    #pragma unroll
    for (int i = 0; i < 8; ++i)
      #pragma unroll
      for (int j = 0; j < 4; ++j)
        acc[i][j] = __builtin_amdgcn_mfma_f32_16x16x32_bf16(af[i], bf[j], acc[i][j], 0, 0, 0);
  }

  // packed epilogue: idx = ((kb*16+h)*16+t)*1024 + half*512 + g*128 + r16*8 + e
  #pragma unroll
  for (int i = 0; i < 8; ++i)
    #pragma unroll
    for (int j = 0; j < 4; ++j)
      #pragma unroll
      for (int rg = 0; rg < 4; ++rg) {
        size_t row = m0 + (wr << 7) + (i << 4) + (g << 2) + rg;
        size_t col = n0 + (wc << 6) + (j << 4) + rr;
        int kb = (int)(row >> 8), t = (int)((row >> 4) & 15), r16 = (int)(row & 15);
        int h = (int)(col >> 6), ch = (int)(col & 63);
        size_t idx = ((((size_t)kb * 16 + h) * 16 + t) << 10)
                   + ((ch >> 5) << 9) + (((ch >> 3) & 3) << 7) + (r16 << 3) + (ch & 7);
        Cpk[idx] = f2bf(acc[i][j][rg]);
      }

  // ---------------- Q-projection coda: one 16x16 tile per block ----------------
  {
    const int mq = wg >> 6, nq = wg & 63;
    const ushort_t* qa = qA + (size_t)(mq * 16 + rr) * 1024 + g * 8;
    const ushort_t* qb = qB + (size_t)(nq * 16 + rr) * 1024 + g * 8;
    f32x4 qacc = (f32x4){0.f, 0.f, 0.f, 0.f};
    #pragma unroll
    for (int kk = 0; kk < 32; ++kk) {
      bf16x8 a = *(const bf16x8*)(qa + kk * 32);
      bf16x8 b = *(const bf16x8*)(qb + kk * 32);
      qacc = __builtin_amdgcn_mfma_f32_16x16x32_bf16(a, b, qacc, 0, 0, 0);
    }
    #pragma unroll
    for (int rg = 0; rg < 4; ++rg)
      qC[(size_t)(mq * 16 + (g << 2) + rg) * 1024 + nq * 16 + rr] = f2bf(qacc[rg]);
  }
}

// ---------------------------------------------------------------------------
// K4a: scores kernel (unchanged: packed K loads, static indexing).
// ---------------------------------------------------------------------------
__global__ __launch_bounds__(256, 3) void scores_kernel(const ushort_t* __restrict__ qp,   // [128][1024]
                                                        const ushort_t* __restrict__ kpk,  // packed
                                                        ushort_t* __restrict__ wbuf) {     // [128][128][256]
  __shared__ float pbuf[2][16][258];

  const int tid = threadIdx.x, lane = tid & 63, wid = tid >> 6;
  const int g = lane >> 4, rr = lane & 15;

  const int b = blockIdx.x;
  const int wg = (b & 7) * 128 + (b >> 3);
  const int kb = wg >> 3;
  const int q0 = (wg & 7) << 4;

  const int hs = wid;

  float w_acc[16][4];
  #pragma unroll
  for (int t = 0; t < 16; ++t)
    #pragma unroll
    for (int r = 0; r < 4; ++r) w_acc[t][r] = 0.f;

  const ushort_t* qrow = qp + (size_t)(q0 + rr) * 1024;
  const ushort_t* kbb  = kpk + ((size_t)kb * 16) * 16384 + g * 128 + rr * 8;

  for (int hp = 0; hp < 4; ++hp) {
    const int h = hp * 4 + hs;
    const int co = h * 64 + g * 8;
    bf16x8 aq0 = *(const bf16x8*)(qrow + co);
    bf16x8 aq1 = *(const bf16x8*)(qrow + co + 32);
    const ushort_t* hb = kbb + (size_t)h * 16384;
    f32x4 s[16];
    #pragma unroll
    for (int t = 0; t < 16; ++t) {
      bf16x8 b0 = *(const bf16x8*)(hb + t * 1024);
      bf16x8 b1 = *(const bf16x8*)(hb + t * 1024 + 512);
      f32x4 a = (f32x4){0.f, 0.f, 0.f, 0.f};
      a = __builtin_amdgcn_mfma_f32_16x16x32_bf16(aq0, b0, a, 0, 0, 0);
      a = __builtin_amdgcn_mfma_f32_16x16x32_bf16(aq1, b1, a, 0, 0, 0);
      s[t] = a;
    }
    #pragma unroll
    for (int r = 0; r < 4; ++r) {
      float mx = s[0][r];
      #pragma unroll
      for (int t = 1; t < 16; ++t) mx = fmaxf(mx, s[t][r]);
      mx = fmaxf(mx, __shfl_xor(mx, 1));
      mx = fmaxf(mx, __shfl_xor(mx, 2));
      mx = fmaxf(mx, __shfl_xor(mx, 4));
      mx = fmaxf(mx, __shfl_xor(mx, 8));
      float sum = 0.f;
      float e[16];
      #pragma unroll
      for (int t = 0; t < 16; ++t) {
        e[t] = __expf((s[t][r] - mx) * 0.125f);
        sum += e[t];
      }
      sum += __shfl_xor(sum, 1);
      sum += __shfl_xor(sum, 2);
      sum += __shfl_xor(sum, 4);
      sum += __shfl_xor(sum, 8);
      float inv = 1.0f / sum;
      #pragma unroll
      for (int t = 0; t < 16; ++t) w_acc[t][r] += e[t] * inv;
    }
  }

  __syncthreads();
  if (hs >= 2) {
    #pragma unroll
    for (int t = 0; t < 16; ++t)
      #pragma unroll
      for (int r = 0; r < 4; ++r)
        pbuf[hs - 2][(g << 2) + r][t * 16 + rr] = w_acc[t][r];
  }
  __syncthreads();
  if (hs < 2) {
    #pragma unroll
    for (int t = 0; t < 16; ++t)
      #pragma unroll
      for (int r = 0; r < 4; ++r)
        w_acc[t][r] += pbuf[hs][(g << 2) + r][t * 16 + rr];
    if (hs == 1) {
      #pragma unroll
      for (int t = 0; t < 16; ++t)
        #pragma unroll
        for (int r = 0; r < 4; ++r)
          pbuf[1][(g << 2) + r][t * 16 + rr] = w_acc[t][r];
    }
  }
  __syncthreads();
  if (hs == 0) {
    ushort_t* wb = wbuf + (size_t)kb * 32768;
    #pragma unroll
    for (int t = 0; t < 16; ++t)
      #pragma unroll
      for (int r = 0; r < 4; ++r) {
        float v = w_acc[t][r] + pbuf[1][(g << 2) + r][t * 16 + rr];
        wb[(size_t)(q0 + (g << 2) + r) * 256 + t * 16 + rr] = f2bf(v);
      }
  }
}

// ---------------------------------------------------------------------------
// K4b: PV kernel (unchanged).
// ---------------------------------------------------------------------------
__global__ __launch_bounds__(256, 4) void pv_kernel(const ushort_t* __restrict__ wbuf, // [128][128][256]
                                                    const float* __restrict__ kx,      // [32768][1024]
                                                    float* __restrict__ xout) {        // [128][128][1024]
  const int tid = threadIdx.x, lane = tid & 63, wid = tid >> 6;
  const int g = lane >> 4, rr = lane & 15;

  const int b = blockIdx.x;
  const int wg = (b & 7) * 128 + (b >> 3);
  const int kb = wg >> 3;
  const int c0 = (wg & 7) * 128;

  const int wr = wid >> 1, wc = wid & 1;

  f32x4 acc[4][4];
  #pragma unroll
  for (int i = 0; i < 4; ++i)
    #pragma unroll
    for (int j = 0; j < 4; ++j) acc[i][j] = (f32x4){0.f, 0.f, 0.f, 0.f};

  const ushort_t* wb = wbuf + (size_t)kb * 32768;
  const float* kxb = kx + (size_t)kb * 256 * 1024;

  for (int nc = 0; nc < 8; ++nc) {
    const int n0 = nc * 32 + g * 8;
    bf16x8 af[4];
    #pragma unroll
    for (int i = 0; i < 4; ++i) {
      int q = (wr << 6) + (i << 4) + rr;
      af[i] = *(const bf16x8*)(wb + (size_t)q * 256 + n0);
    }
    #pragma unroll
    for (int j = 0; j < 4; ++j) {
      int c = c0 + (wc << 6) + (j << 4) + rr;
      const float* src = kxb + (size_t)n0 * 1024 + c;
      float f[8];
      #pragma unroll
      for (int jj = 0; jj < 8; ++jj) f[jj] = src[(size_t)jj * 1024];
      bf16x8 bb;
      #pragma unroll
      for (int jj = 0; jj < 8; ++jj) bb[jj] = (__bf16)f[jj];
      #pragma unroll
      for (int i = 0; i < 4; ++i)
        acc[i][j] = __builtin_amdgcn_mfma_f32_16x16x32_bf16(af[i], bb, acc[i][j], 0, 0, 0);
    }
  }

  #pragma unroll
  for (int i = 0; i < 4; ++i)
    #pragma unroll
    for (int j = 0; j < 4; ++j)
      #pragma unroll
      for (int rg = 0; rg < 4; ++rg) {
        int q = (wr << 6) + (i << 4) + (g << 2) + rg;
        int c = c0 + (wc << 6) + (j << 4) + rr;
        xout[((size_t)q * 128 + kb) * 1024 + c] = acc[i][j][rg];
      }
}

// ---------------------------------------------------------------------------
// launcher
// ---------------------------------------------------------------------------
extern "C" void kernel_launch(void* const* d_in, const int* in_sizes, int n_in,
                              void* d_out, int out_size, void* d_ws, size_t ws_size,
                              hipStream_t stream) {
  const float* qx = (const float*)d_in[0];
  const float* kx = (const float*)d_in[1];
  const float* gq = (const float*)d_in[2];
  const float* bq = (const float*)d_in[3];
  const float* gk = (const float*)d_in[4];
  const float* bk = (const float*)d_in[5];
  const float* Wq = (const float*)d_in[6];
  const float* Wk = (const float*)d_in[7];

  char* ws = (char*)d_ws;
  // ws layout (total 72.25 MiB):
  //   [0, 64M)            kkp   : PACKED K-projection bf16 (live: gemm256 -> scores)
  //   [64M, 64M+256K)     qproj : Q-projection bf16 [128][1024]    (live: gemm256 -> scores)
  //   [64M+256K, +8M)     wbuf  : head-summed weights bf16 [128][128][256] (live: scores -> pv)
  //     aliased inside wbuf (dead before scores runs):
  //       qln  @wbuf+0     [128][1024] bf16   (live: ln -> gemm256)
  //       Wqb  @wbuf+256K  [1024][1024] bf16  (live: cvt -> gemm256)
  //       Wkb  @wbuf+2.25M [1024][1024] bf16  (live: cvt -> gemm256)
  ushort_t* kkp   = (ushort_t*)(ws);
  ushort_t* qproj = (ushort_t*)(ws + 67108864);
  ushort_t* wbuf  = (ushort_t*)(ws + 67371008);
  ushort_t* qln   = (ushort_t*)(ws + 67371008);
  ushort_t* Wqb   = (ushort_t*)(ws + 67371008 + 262144);
  ushort_t* Wkb   = (ushort_t*)(ws + 67371008 + 2359296);
  // kln (bf16, 64 MiB) lives in d_out; dead after gemm256, overwritten by pv.
  ushort_t* kln  = (ushort_t*)d_out;
  float*    xout = (float*)d_out;

  cvt_bf16_kernel<<<1024, 256, 0, stream>>>(Wq, Wqb, 262144);
  cvt_bf16_kernel<<<1024, 256, 0, stream>>>(Wk, Wkb, 262144);
  ln_kernel<<<32896, 256, 0, stream>>>(kx, qx, gk, bk, gq, bq, kln, qln);
  gemm256_kernel<<<512, 512, 0, stream>>>(kln, Wkb, kkp, qln, Wqb, qproj, 32768, 1024);
  scores_kernel<<<1024, 256, 0, stream>>>(qproj, kkp, wbuf);
  pv_kernel<<<1024, 256, 0, stream>>>(wbuf, kx, xout);
}

// Round 11
// 280.653 us; speedup vs baseline: 3.3247x; 1.0245x over previous
//
#include <hip/hip_runtime.h>

// Problem constants: Bq=128, Bk=128, Nk=256, C=1024, H=16, hd=64, scale=0.125, eps=1e-5.

typedef unsigned short ushort_t;
typedef __bf16 bf16x8 __attribute__((ext_vector_type(8)));
typedef float f32x4 __attribute__((ext_vector_type(4)));

#define AS1 __attribute__((address_space(1)))
#define AS3 __attribute__((address_space(3)))

__device__ __forceinline__ void gload_lds16(const void* g, void* l) {
  __builtin_amdgcn_global_load_lds((const AS1 unsigned int*)g, (AS3 unsigned int*)l, 16, 0, 0);
}

__device__ __forceinline__ ushort_t f2bf(float f) {
  unsigned u = __float_as_uint(f);
  unsigned r = u + 0x7FFFu + ((u >> 16) & 1u);
  return (ushort_t)(r >> 16);
}

// ---------------------------------------------------------------------------
// K0: fp32 -> bf16 convert (for Wq / Wk)
// ---------------------------------------------------------------------------
__global__ __launch_bounds__(256) void cvt_bf16_kernel(const float* __restrict__ src,
                                                       ushort_t* __restrict__ dst, int n4) {
  int i = blockIdx.x * 256 + threadIdx.x;
  if (i < n4) {
    float4 v = ((const float4*)src)[i];
    ushort4 o;
    o.x = f2bf(v.x); o.y = f2bf(v.y); o.z = f2bf(v.z); o.w = f2bf(v.w);
    ((ushort4*)dst)[i] = o;
  }
}

// ---------------------------------------------------------------------------
// K1: LayerNorm rows -> bf16.  rows 0..32767: kx -> kln; rows 32768+: qx -> qln
// ---------------------------------------------------------------------------
__global__ __launch_bounds__(256) void ln_kernel(const float* __restrict__ kx,
                                                 const float* __restrict__ qx,
                                                 const float* __restrict__ gk,
                                                 const float* __restrict__ bk,
                                                 const float* __restrict__ gq,
                                                 const float* __restrict__ bq,
                                                 ushort_t* __restrict__ kln,
                                                 ushort_t* __restrict__ qln) {
  int row = blockIdx.x;
  const float* src; ushort_t* dst; const float* g; const float* bb;
  if (row < 32768) {
    src = kx + (size_t)row * 1024; dst = kln + (size_t)row * 1024; g = gk; bb = bk;
  } else {
    int r = row - 32768;
    src = qx + (size_t)r * 1024; dst = qln + (size_t)r * 1024; g = gq; bb = bq;
  }
  int tid = threadIdx.x;
  float4 v = ((const float4*)src)[tid];
  float s  = v.x + v.y + v.z + v.w;
  float s2 = v.x*v.x + v.y*v.y + v.z*v.z + v.w*v.w;
  #pragma unroll
  for (int off = 1; off < 64; off <<= 1) {
    s  += __shfl_xor(s, off);
    s2 += __shfl_xor(s2, off);
  }
  __shared__ float red[8];
  int wid = tid >> 6, lane = tid & 63;
  if (lane == 0) { red[wid] = s; red[4 + wid] = s2; }
  __syncthreads();
  s  = red[0] + red[1] + red[2] + red[3];
  s2 = red[4] + red[5] + red[6] + red[7];
  float mean = s * (1.0f / 1024.0f);
  float var  = s2 * (1.0f / 1024.0f) - mean * mean;
  float rstd = rsqrtf(var + 1e-5f);
  float4 gg = ((const float4*)g)[tid];
  float4 b4 = ((const float4*)bb)[tid];
  ushort4 o;
  o.x = f2bf((v.x - mean) * rstd * gg.x + b4.x);
  o.y = f2bf((v.y - mean) * rstd * gg.y + b4.y);
  o.z = f2bf((v.z - mean) * rstd * gg.z + b4.z);
  o.w = f2bf((v.w - mean) * rstd * gg.w + b4.w);
  ((ushort4*)dst)[tid] = o;
}

// ---------------------------------------------------------------------------
// K3: merged GEMM kernel, 512 blocks x 512 thr (8 waves), 1 block/CU (LDS 128K).
// Main: 256x256-tile K-projection, BK=32, FOUR LDS buffers, depth-3 prefetch
//   (r7-measured 85.6us): per K-tile two phases x 16 MFMA, one s_barrier per
//   phase, vmcnt(8) once per tile (never 0 in main loop).
//   Packed-fragment epilogue for scores.
// Coda: each block computes ONE 16x16 Q-projection tile (8m x 64n = 512).
// Launch bound (512,2): cap 256 VGPR — (512,4) spilled 30x (r9).
// ---------------------------------------------------------------------------
__global__ __launch_bounds__(512, 2) void gemm256_kernel(const ushort_t* __restrict__ A,
                                                         const ushort_t* __restrict__ Bt,
                                                         ushort_t* __restrict__ Cpk,
                                                         const ushort_t* __restrict__ qA,
                                                         const ushort_t* __restrict__ qB,
                                                         ushort_t* __restrict__ qC,
                                                         int M, int N) {
  __shared__ ushort_t lds[4][2][256 * 32];

  const int tid = threadIdx.x, lane = tid & 63, wid = tid >> 6;
  const int g = lane >> 4, rr = lane & 15;
  const int wr = wid >> 2, wc = wid & 3;

  const int Mt = M >> 8, Nt = N >> 8;
  const int nwg = Mt * Nt;
  const int qq = nwg >> 3, r8 = nwg & 7;
  const int xcd = blockIdx.x & 7, idx = blockIdx.x >> 3;
  const int wg = (xcd < r8 ? xcd * (qq + 1) : r8 * (qq + 1) + (xcd - r8) * qq) + idx;
  const int mt = wg / Nt, nt = wg - mt * Nt;
  const size_t m0 = (size_t)mt << 8, n0 = (size_t)nt << 8;

  const int s_r  = lane >> 2;
  const int s_gr = (lane & 3) ^ (s_r & 3);

  const ushort_t* Abase = A  + m0 * 1024;
  const ushort_t* Bbase = Bt + n0 * 1024;

  f32x4 acc[8][4];
  #pragma unroll
  for (int i = 0; i < 8; ++i)
    #pragma unroll
    for (int j = 0; j < 4; ++j) acc[i][j] = (f32x4){0.f, 0.f, 0.f, 0.f};

  auto stageA = [&](int kt) {
    const int k0 = kt << 5;
    ushort_t* dst = &lds[kt & 3][0][0];
    #pragma unroll
    for (int it = 0; it < 2; ++it) {
      int ci = (wid << 1) | it;
      int r  = (ci << 4) + s_r;
      gload_lds16(Abase + (size_t)r * 1024 + k0 + (s_gr << 3), dst + (ci << 9));
    }
  };
  auto stageB = [&](int kt) {
    const int k0 = kt << 5;
    ushort_t* dst = &lds[kt & 3][1][0];
    #pragma unroll
    for (int it = 0; it < 2; ++it) {
      int ci = (wid << 1) | it;
      int r  = (ci << 4) + s_r;
      gload_lds16(Bbase + (size_t)r * 1024 + k0 + (s_gr << 3), dst + (ci << 9));
    }
  };

  // prologue: tiles 0,1,2 in flight (12 loads/thread); retire tile 0 (vmcnt(8)).
  stageA(0); stageB(0); stageA(1); stageB(1); stageA(2); stageB(2);
  asm volatile("s_waitcnt vmcnt(8)" ::: "memory");
  __builtin_amdgcn_s_barrier();

  const int rsw = rr & 3;

  #pragma unroll 1
  for (int u = 0; u < 29; ++u) {
    const ushort_t* as = &lds[u & 3][0][0];
    const ushort_t* bs = &lds[u & 3][1][0];
    bf16x8 af[8];
    // ---- even phase: A-frags + B j=0,1; stage A(u+3); 16 MFMA ----
    {
      #pragma unroll
      for (int i = 0; i < 8; ++i) {
        int r = (wr << 7) + (i << 4) + rr;
        af[i] = *(const bf16x8*)&as[(r << 5) + ((g ^ rsw) << 3)];
      }
      int r0 = (wc << 6) + rr;
      bf16x8 b0 = *(const bf16x8*)&bs[(r0 << 5) + ((g ^ rsw) << 3)];
      int r1 = (wc << 6) + 16 + rr;
      bf16x8 b1 = *(const bf16x8*)&bs[(r1 << 5) + ((g ^ rsw) << 3)];
      stageA(u + 3);
      __builtin_amdgcn_s_setprio(1);
      #pragma unroll
      for (int i = 0; i < 8; ++i) {
        acc[i][0] = __builtin_amdgcn_mfma_f32_16x16x32_bf16(af[i], b0, acc[i][0], 0, 0, 0);
        acc[i][1] = __builtin_amdgcn_mfma_f32_16x16x32_bf16(af[i], b1, acc[i][1], 0, 0, 0);
      }
      __builtin_amdgcn_s_setprio(0);
      __builtin_amdgcn_s_barrier();
    }
    // ---- odd phase: B j=2,3 (reuse af); stage B(u+3); 16 MFMA; vmcnt(8) ----
    {
      int r2 = (wc << 6) + 32 + rr;
      bf16x8 b2 = *(const bf16x8*)&bs[(r2 << 5) + ((g ^ rsw) << 3)];
      int r3 = (wc << 6) + 48 + rr;
      bf16x8 b3 = *(const bf16x8*)&bs[(r3 << 5) + ((g ^ rsw) << 3)];
      stageB(u + 3);
      __builtin_amdgcn_s_setprio(1);
      #pragma unroll
      for (int i = 0; i < 8; ++i) {
        acc[i][2] = __builtin_amdgcn_mfma_f32_16x16x32_bf16(af[i], b2, acc[i][2], 0, 0, 0);
        acc[i][3] = __builtin_amdgcn_mfma_f32_16x16x32_bf16(af[i], b3, acc[i][3], 0, 0, 0);
      }
      __builtin_amdgcn_s_setprio(0);
      asm volatile("s_waitcnt vmcnt(8)" ::: "memory");
      __builtin_amdgcn_s_barrier();
    }
  }

  // drain: tiles 30,31 still in flight -> one vmcnt(0), then no more staging.
  asm volatile("s_waitcnt vmcnt(0)" ::: "memory");
  __builtin_amdgcn_s_barrier();
  #pragma unroll 1
  for (int u = 29; u < 32; ++u) {
    const ushort_t* as = &lds[u & 3][0][0];
    const ushort_t* bs = &lds[u & 3][1][0];
    bf16x8 af2[8], bfj[4];
    #pragma unroll
    for (int i = 0; i < 8; ++i) {
      int r = (wr << 7) + (i << 4) + rr;
      af2[i] = *(const bf16x8*)&as[(r << 5) + ((g ^ rsw) << 3)];
    }
    #pragma unroll
    for (int j = 0; j < 4; ++j) {
      int r = (wc << 6) + (j << 4) + rr;
      bfj[j] = *(const bf16x8*)&bs[(r << 5) + ((g ^ rsw) << 3)];
    }
    #pragma unroll
    for (int i = 0; i < 8; ++i)
      #pragma unroll
      for (int j = 0; j < 4; ++j)
        acc[i][j] = __builtin_amdgcn_mfma_f32_16x16x32_bf16(af2[i], bfj[j], acc[i][j], 0, 0, 0);
  }

  // packed epilogue: idx = ((kb*16+h)*16+t)*1024 + half*512 + g*128 + r16*8 + e
  #pragma unroll
  for (int i = 0; i < 8; ++i)
    #pragma unroll
    for (int j = 0; j < 4; ++j)
      #pragma unroll
      for (int rg = 0; rg < 4; ++rg) {
        size_t row = m0 + (wr << 7) + (i << 4) + (g << 2) + rg;
        size_t col = n0 + (wc << 6) + (j << 4) + rr;
        int kb = (int)(row >> 8), t = (int)((row >> 4) & 15), r16 = (int)(row & 15);
        int h = (int)(col >> 6), ch = (int)(col & 63);
        size_t idx = ((((size_t)kb * 16 + h) * 16 + t) << 10)
                   + ((ch >> 5) << 9) + (((ch >> 3) & 3) << 7) + (r16 << 3) + (ch & 7);
        Cpk[idx] = f2bf(acc[i][j][rg]);
      }

  // ---------------- Q-projection coda: one 16x16 tile per block ----------------
  {
    const int mq = wg >> 6, nq = wg & 63;
    const ushort_t* qa = qA + (size_t)(mq * 16 + rr) * 1024 + g * 8;
    const ushort_t* qb = qB + (size_t)(nq * 16 + rr) * 1024 + g * 8;
    f32x4 qacc = (f32x4){0.f, 0.f, 0.f, 0.f};
    #pragma unroll
    for (int kk = 0; kk < 32; ++kk) {
      bf16x8 a = *(const bf16x8*)(qa + kk * 32);
      bf16x8 b = *(const bf16x8*)(qb + kk * 32);
      qacc = __builtin_amdgcn_mfma_f32_16x16x32_bf16(a, b, qacc, 0, 0, 0);
    }
    #pragma unroll
    for (int rg = 0; rg < 4; ++rg)
      qC[(size_t)(mq * 16 + (g << 2) + rg) * 1024 + nq * 16 + rr] = f2bf(qacc[rg]);
  }
}

// ---------------------------------------------------------------------------
// K4a: scores kernel (unchanged: packed K loads, static indexing).
// ---------------------------------------------------------------------------
__global__ __launch_bounds__(256, 3) void scores_kernel(const ushort_t* __restrict__ qp,   // [128][1024]
                                                        const ushort_t* __restrict__ kpk,  // packed
                                                        ushort_t* __restrict__ wbuf) {     // [128][128][256]
  __shared__ float pbuf[2][16][258];

  const int tid = threadIdx.x, lane = tid & 63, wid = tid >> 6;
  const int g = lane >> 4, rr = lane & 15;

  const int b = blockIdx.x;
  const int wg = (b & 7) * 128 + (b >> 3);
  const int kb = wg >> 3;
  const int q0 = (wg & 7) << 4;

  const int hs = wid;

  float w_acc[16][4];
  #pragma unroll
  for (int t = 0; t < 16; ++t)
    #pragma unroll
    for (int r = 0; r < 4; ++r) w_acc[t][r] = 0.f;

  const ushort_t* qrow = qp + (size_t)(q0 + rr) * 1024;
  const ushort_t* kbb  = kpk + ((size_t)kb * 16) * 16384 + g * 128 + rr * 8;

  for (int hp = 0; hp < 4; ++hp) {
    const int h = hp * 4 + hs;
    const int co = h * 64 + g * 8;
    bf16x8 aq0 = *(const bf16x8*)(qrow + co);
    bf16x8 aq1 = *(const bf16x8*)(qrow + co + 32);
    const ushort_t* hb = kbb + (size_t)h * 16384;
    f32x4 s[16];
    #pragma unroll
    for (int t = 0; t < 16; ++t) {
      bf16x8 b0 = *(const bf16x8*)(hb + t * 1024);
      bf16x8 b1 = *(const bf16x8*)(hb + t * 1024 + 512);
      f32x4 a = (f32x4){0.f, 0.f, 0.f, 0.f};
      a = __builtin_amdgcn_mfma_f32_16x16x32_bf16(aq0, b0, a, 0, 0, 0);
      a = __builtin_amdgcn_mfma_f32_16x16x32_bf16(aq1, b1, a, 0, 0, 0);
      s[t] = a;
    }
    #pragma unroll
    for (int r = 0; r < 4; ++r) {
      float mx = s[0][r];
      #pragma unroll
      for (int t = 1; t < 16; ++t) mx = fmaxf(mx, s[t][r]);
      mx = fmaxf(mx, __shfl_xor(mx, 1));
      mx = fmaxf(mx, __shfl_xor(mx, 2));
      mx = fmaxf(mx, __shfl_xor(mx, 4));
      mx = fmaxf(mx, __shfl_xor(mx, 8));
      float sum = 0.f;
      float e[16];
      #pragma unroll
      for (int t = 0; t < 16; ++t) {
        e[t] = __expf((s[t][r] - mx) * 0.125f);
        sum += e[t];
      }
      sum += __shfl_xor(sum, 1);
      sum += __shfl_xor(sum, 2);
      sum += __shfl_xor(sum, 4);
      sum += __shfl_xor(sum, 8);
      float inv = 1.0f / sum;
      #pragma unroll
      for (int t = 0; t < 16; ++t) w_acc[t][r] += e[t] * inv;
    }
  }

  __syncthreads();
  if (hs >= 2) {
    #pragma unroll
    for (int t = 0; t < 16; ++t)
      #pragma unroll
      for (int r = 0; r < 4; ++r)
        pbuf[hs - 2][(g << 2) + r][t * 16 + rr] = w_acc[t][r];
  }
  __syncthreads();
  if (hs < 2) {
    #pragma unroll
    for (int t = 0; t < 16; ++t)
      #pragma unroll
      for (int r = 0; r < 4; ++r)
        w_acc[t][r] += pbuf[hs][(g << 2) + r][t * 16 + rr];
    if (hs == 1) {
      #pragma unroll
      for (int t = 0; t < 16; ++t)
        #pragma unroll
        for (int r = 0; r < 4; ++r)
          pbuf[1][(g << 2) + r][t * 16 + rr] = w_acc[t][r];
    }
  }
  __syncthreads();
  if (hs == 0) {
    ushort_t* wb = wbuf + (size_t)kb * 32768;
    #pragma unroll
    for (int t = 0; t < 16; ++t)
      #pragma unroll
      for (int r = 0; r < 4; ++r) {
        float v = w_acc[t][r] + pbuf[1][(g << 2) + r][t * 16 + rr];
        wb[(size_t)(q0 + (g << 2) + r) * 256 + t * 16 + rr] = f2bf(v);
      }
  }
}

// ---------------------------------------------------------------------------
// K4b: PV kernel (unchanged).
// ---------------------------------------------------------------------------
__global__ __launch_bounds__(256, 4) void pv_kernel(const ushort_t* __restrict__ wbuf, // [128][128][256]
                                                    const float* __restrict__ kx,      // [32768][1024]
                                                    float* __restrict__ xout) {        // [128][128][1024]
  const int tid = threadIdx.x, lane = tid & 63, wid = tid >> 6;
  const int g = lane >> 4, rr = lane & 15;

  const int b = blockIdx.x;
  const int wg = (b & 7) * 128 + (b >> 3);
  const int kb = wg >> 3;
  const int c0 = (wg & 7) * 128;

  const int wr = wid >> 1, wc = wid & 1;

  f32x4 acc[4][4];
  #pragma unroll
  for (int i = 0; i < 4; ++i)
    #pragma unroll
    for (int j = 0; j < 4; ++j) acc[i][j] = (f32x4){0.f, 0.f, 0.f, 0.f};

  const ushort_t* wb = wbuf + (size_t)kb * 32768;
  const float* kxb = kx + (size_t)kb * 256 * 1024;

  for (int nc = 0; nc < 8; ++nc) {
    const int n0 = nc * 32 + g * 8;
    bf16x8 af[4];
    #pragma unroll
    for (int i = 0; i < 4; ++i) {
      int q = (wr << 6) + (i << 4) + rr;
      af[i] = *(const bf16x8*)(wb + (size_t)q * 256 + n0);
    }
    #pragma unroll
    for (int j = 0; j < 4; ++j) {
      int c = c0 + (wc << 6) + (j << 4) + rr;
      const float* src = kxb + (size_t)n0 * 1024 + c;
      float f[8];
      #pragma unroll
      for (int jj = 0; jj < 8; ++jj) f[jj] = src[(size_t)jj * 1024];
      bf16x8 bb;
      #pragma unroll
      for (int jj = 0; jj < 8; ++jj) bb[jj] = (__bf16)f[jj];
      #pragma unroll
      for (int i = 0; i < 4; ++i)
        acc[i][j] = __builtin_amdgcn_mfma_f32_16x16x32_bf16(af[i], bb, acc[i][j], 0, 0, 0);
    }
  }

  #pragma unroll
  for (int i = 0; i < 4; ++i)
    #pragma unroll
    for (int j = 0; j < 4; ++j)
      #pragma unroll
      for (int rg = 0; rg < 4; ++rg) {
        int q = (wr << 6) + (i << 4) + (g << 2) + rg;
        int c = c0 + (wc << 6) + (j << 4) + rr;
        xout[((size_t)q * 128 + kb) * 1024 + c] = acc[i][j][rg];
      }
}

// ---------------------------------------------------------------------------
// launcher
// ---------------------------------------------------------------------------
extern "C" void kernel_launch(void* const* d_in, const int* in_sizes, int n_in,
                              void* d_out, int out_size, void* d_ws, size_t ws_size,
                              hipStream_t stream) {
  const float* qx = (const float*)d_in[0];
  const float* kx = (const float*)d_in[1];
  const float* gq = (const float*)d_in[2];
  const float* bq = (const float*)d_in[3];
  const float* gk = (const float*)d_in[4];
  const float* bk = (const float*)d_in[5];
  const float* Wq = (const float*)d_in[6];
  const float* Wk = (const float*)d_in[7];

  char* ws = (char*)d_ws;
  // ws layout (total 72.25 MiB):
  //   [0, 64M)            kkp   : PACKED K-projection bf16 (live: gemm256 -> scores)
  //   [64M, 64M+256K)     qproj : Q-projection bf16 [128][1024]    (live: gemm256 -> scores)
  //   [64M+256K, +8M)     wbuf  : head-summed weights bf16 [128][128][256] (live: scores -> pv)
  //     aliased inside wbuf (dead before scores runs):
  //       qln  @wbuf+0     [128][1024] bf16   (live: ln -> gemm256)
  //       Wqb  @wbuf+256K  [1024][1024] bf16  (live: cvt -> gemm256)
  //       Wkb  @wbuf+2.25M [1024][1024] bf16  (live: cvt -> gemm256)
  ushort_t* kkp   = (ushort_t*)(ws);
  ushort_t* qproj = (ushort_t*)(ws + 67108864);
  ushort_t* wbuf  = (ushort_t*)(ws + 67371008);
  ushort_t* qln   = (ushort_t*)(ws + 67371008);
  ushort_t* Wqb   = (ushort_t*)(ws + 67371008 + 262144);
  ushort_t* Wkb   = (ushort_t*)(ws + 67371008 + 2359296);
  // kln (bf16, 64 MiB) lives in d_out; dead after gemm256, overwritten by pv.
  ushort_t* kln  = (ushort_t*)d_out;
  float*    xout = (float*)d_out;

  cvt_bf16_kernel<<<1024, 256, 0, stream>>>(Wq, Wqb, 262144);
  cvt_bf16_kernel<<<1024, 256, 0, stream>>>(Wk, Wkb, 262144);
  ln_kernel<<<32896, 256, 0, stream>>>(kx, qx, gk, bk, gq, bq, kln, qln);
  gemm256_kernel<<<512, 512, 0, stream>>>(kln, Wkb, kkp, qln, Wqb, qproj, 32768, 1024);
  scores_kernel<<<1024, 256, 0, stream>>>(qproj, kkp, wbuf);
  pv_kernel<<<1024, 256, 0, stream>>>(wbuf, kx, xout);
}

// Round 12
// 265.972 us; speedup vs baseline: 3.5082x; 1.0552x over previous
//
#include <hip/hip_runtime.h>

// Problem constants: Bq=128, Bk=128, Nk=256, C=1024, H=16, hd=64, scale=0.125, eps=1e-5.

typedef unsigned short ushort_t;
typedef __bf16 bf16x8 __attribute__((ext_vector_type(8)));
typedef float f32x4 __attribute__((ext_vector_type(4)));

#define AS1 __attribute__((address_space(1)))
#define AS3 __attribute__((address_space(3)))

__device__ __forceinline__ void gload_lds16(const void* g, void* l) {
  __builtin_amdgcn_global_load_lds((const AS1 unsigned int*)g, (AS3 unsigned int*)l, 16, 0, 0);
}

__device__ __forceinline__ ushort_t f2bf(float f) {
  unsigned u = __float_as_uint(f);
  unsigned r = u + 0x7FFFu + ((u >> 16) & 1u);
  return (ushort_t)(r >> 16);
}

// ---------------------------------------------------------------------------
// K0: fp32 -> bf16 convert (for Wq / Wk)
// ---------------------------------------------------------------------------
__global__ __launch_bounds__(256) void cvt_bf16_kernel(const float* __restrict__ src,
                                                       ushort_t* __restrict__ dst, int n4) {
  int i = blockIdx.x * 256 + threadIdx.x;
  if (i < n4) {
    float4 v = ((const float4*)src)[i];
    ushort4 o;
    o.x = f2bf(v.x); o.y = f2bf(v.y); o.z = f2bf(v.z); o.w = f2bf(v.w);
    ((ushort4*)dst)[i] = o;
  }
}

// ---------------------------------------------------------------------------
// K1: LayerNorm rows -> bf16.  rows 0..32767: kx -> kln; rows 32768+: qx -> qln
// ---------------------------------------------------------------------------
__global__ __launch_bounds__(256) void ln_kernel(const float* __restrict__ kx,
                                                 const float* __restrict__ qx,
                                                 const float* __restrict__ gk,
                                                 const float* __restrict__ bk,
                                                 const float* __restrict__ gq,
                                                 const float* __restrict__ bq,
                                                 ushort_t* __restrict__ kln,
                                                 ushort_t* __restrict__ qln) {
  int row = blockIdx.x;
  const float* src; ushort_t* dst; const float* g; const float* bb;
  if (row < 32768) {
    src = kx + (size_t)row * 1024; dst = kln + (size_t)row * 1024; g = gk; bb = bk;
  } else {
    int r = row - 32768;
    src = qx + (size_t)r * 1024; dst = qln + (size_t)r * 1024; g = gq; bb = bq;
  }
  int tid = threadIdx.x;
  float4 v = ((const float4*)src)[tid];
  float s  = v.x + v.y + v.z + v.w;
  float s2 = v.x*v.x + v.y*v.y + v.z*v.z + v.w*v.w;
  #pragma unroll
  for (int off = 1; off < 64; off <<= 1) {
    s  += __shfl_xor(s, off);
    s2 += __shfl_xor(s2, off);
  }
  __shared__ float red[8];
  int wid = tid >> 6, lane = tid & 63;
  if (lane == 0) { red[wid] = s; red[4 + wid] = s2; }
  __syncthreads();
  s  = red[0] + red[1] + red[2] + red[3];
  s2 = red[4] + red[5] + red[6] + red[7];
  float mean = s * (1.0f / 1024.0f);
  float var  = s2 * (1.0f / 1024.0f) - mean * mean;
  float rstd = rsqrtf(var + 1e-5f);
  float4 gg = ((const float4*)g)[tid];
  float4 b4 = ((const float4*)bb)[tid];
  ushort4 o;
  o.x = f2bf((v.x - mean) * rstd * gg.x + b4.x);
  o.y = f2bf((v.y - mean) * rstd * gg.y + b4.y);
  o.z = f2bf((v.z - mean) * rstd * gg.z + b4.z);
  o.w = f2bf((v.w - mean) * rstd * gg.w + b4.w);
  ((ushort4*)dst)[tid] = o;
}

// ---------------------------------------------------------------------------
// K3: merged GEMM kernel, 512 blocks x 512 thr (8 waves), 1 block/CU (LDS 128K).
// Main: 256x256-tile K-projection, BK=32, FOUR LDS buffers, depth-3 prefetch
//   (r7-measured 85.6us). Packed-fragment epilogue for scores.
// Coda: ONLY blocks with (wg&63)<8 (8 per XCD, 64 total); each WAVE computes a
//   DIFFERENT 16x16 Q-tile: ti = (wg>>6)*64 + (wg&7)*8 + wid (bijective 0..511).
//   r11's all-block redundant coda cost +23us; this is 64x less work.
// Launch bound (512,2): cap 256 VGPR — (512,4) spilled 30x (r9).
// ---------------------------------------------------------------------------
__global__ __launch_bounds__(512, 2) void gemm256_kernel(const ushort_t* __restrict__ A,
                                                         const ushort_t* __restrict__ Bt,
                                                         ushort_t* __restrict__ Cpk,
                                                         const ushort_t* __restrict__ qA,
                                                         const ushort_t* __restrict__ qB,
                                                         ushort_t* __restrict__ qC,
                                                         int M, int N) {
  __shared__ ushort_t lds[4][2][256 * 32];

  const int tid = threadIdx.x, lane = tid & 63, wid = tid >> 6;
  const int g = lane >> 4, rr = lane & 15;
  const int wr = wid >> 2, wc = wid & 3;

  const int Mt = M >> 8, Nt = N >> 8;
  const int nwg = Mt * Nt;
  const int qq = nwg >> 3, r8 = nwg & 7;
  const int xcd = blockIdx.x & 7, idx = blockIdx.x >> 3;
  const int wg = (xcd < r8 ? xcd * (qq + 1) : r8 * (qq + 1) + (xcd - r8) * qq) + idx;
  const int mt = wg / Nt, nt = wg - mt * Nt;
  const size_t m0 = (size_t)mt << 8, n0 = (size_t)nt << 8;

  const int s_r  = lane >> 2;
  const int s_gr = (lane & 3) ^ (s_r & 3);

  const ushort_t* Abase = A  + m0 * 1024;
  const ushort_t* Bbase = Bt + n0 * 1024;

  f32x4 acc[8][4];
  #pragma unroll
  for (int i = 0; i < 8; ++i)
    #pragma unroll
    for (int j = 0; j < 4; ++j) acc[i][j] = (f32x4){0.f, 0.f, 0.f, 0.f};

  auto stageA = [&](int kt) {
    const int k0 = kt << 5;
    ushort_t* dst = &lds[kt & 3][0][0];
    #pragma unroll
    for (int it = 0; it < 2; ++it) {
      int ci = (wid << 1) | it;
      int r  = (ci << 4) + s_r;
      gload_lds16(Abase + (size_t)r * 1024 + k0 + (s_gr << 3), dst + (ci << 9));
    }
  };
  auto stageB = [&](int kt) {
    const int k0 = kt << 5;
    ushort_t* dst = &lds[kt & 3][1][0];
    #pragma unroll
    for (int it = 0; it < 2; ++it) {
      int ci = (wid << 1) | it;
      int r  = (ci << 4) + s_r;
      gload_lds16(Bbase + (size_t)r * 1024 + k0 + (s_gr << 3), dst + (ci << 9));
    }
  };

  // prologue: tiles 0,1,2 in flight (12 loads/thread); retire tile 0 (vmcnt(8)).
  stageA(0); stageB(0); stageA(1); stageB(1); stageA(2); stageB(2);
  asm volatile("s_waitcnt vmcnt(8)" ::: "memory");
  __builtin_amdgcn_s_barrier();

  const int rsw = rr & 3;

  #pragma unroll 1
  for (int u = 0; u < 29; ++u) {
    const ushort_t* as = &lds[u & 3][0][0];
    const ushort_t* bs = &lds[u & 3][1][0];
    bf16x8 af[8];
    // ---- even phase: A-frags + B j=0,1; stage A(u+3); 16 MFMA ----
    {
      #pragma unroll
      for (int i = 0; i < 8; ++i) {
        int r = (wr << 7) + (i << 4) + rr;
        af[i] = *(const bf16x8*)&as[(r << 5) + ((g ^ rsw) << 3)];
      }
      int r0 = (wc << 6) + rr;
      bf16x8 b0 = *(const bf16x8*)&bs[(r0 << 5) + ((g ^ rsw) << 3)];
      int r1 = (wc << 6) + 16 + rr;
      bf16x8 b1 = *(const bf16x8*)&bs[(r1 << 5) + ((g ^ rsw) << 3)];
      stageA(u + 3);
      __builtin_amdgcn_s_setprio(1);
      #pragma unroll
      for (int i = 0; i < 8; ++i) {
        acc[i][0] = __builtin_amdgcn_mfma_f32_16x16x32_bf16(af[i], b0, acc[i][0], 0, 0, 0);
        acc[i][1] = __builtin_amdgcn_mfma_f32_16x16x32_bf16(af[i], b1, acc[i][1], 0, 0, 0);
      }
      __builtin_amdgcn_s_setprio(0);
      __builtin_amdgcn_s_barrier();
    }
    // ---- odd phase: B j=2,3 (reuse af); stage B(u+3); 16 MFMA; vmcnt(8) ----
    {
      int r2 = (wc << 6) + 32 + rr;
      bf16x8 b2 = *(const bf16x8*)&bs[(r2 << 5) + ((g ^ rsw) << 3)];
      int r3 = (wc << 6) + 48 + rr;
      bf16x8 b3 = *(const bf16x8*)&bs[(r3 << 5) + ((g ^ rsw) << 3)];
      stageB(u + 3);
      __builtin_amdgcn_s_setprio(1);
      #pragma unroll
      for (int i = 0; i < 8; ++i) {
        acc[i][2] = __builtin_amdgcn_mfma_f32_16x16x32_bf16(af[i], b2, acc[i][2], 0, 0, 0);
        acc[i][3] = __builtin_amdgcn_mfma_f32_16x16x32_bf16(af[i], b3, acc[i][3], 0, 0, 0);
      }
      __builtin_amdgcn_s_setprio(0);
      asm volatile("s_waitcnt vmcnt(8)" ::: "memory");
      __builtin_amdgcn_s_barrier();
    }
  }

  // drain: tiles 30,31 still in flight -> one vmcnt(0), then no more staging.
  asm volatile("s_waitcnt vmcnt(0)" ::: "memory");
  __builtin_amdgcn_s_barrier();
  #pragma unroll 1
  for (int u = 29; u < 32; ++u) {
    const ushort_t* as = &lds[u & 3][0][0];
    const ushort_t* bs = &lds[u & 3][1][0];
    bf16x8 af2[8], bfj[4];
    #pragma unroll
    for (int i = 0; i < 8; ++i) {
      int r = (wr << 7) + (i << 4) + rr;
      af2[i] = *(const bf16x8*)&as[(r << 5) + ((g ^ rsw) << 3)];
    }
    #pragma unroll
    for (int j = 0; j < 4; ++j) {
      int r = (wc << 6) + (j << 4) + rr;
      bfj[j] = *(const bf16x8*)&bs[(r << 5) + ((g ^ rsw) << 3)];
    }
    #pragma unroll
    for (int i = 0; i < 8; ++i)
      #pragma unroll
      for (int j = 0; j < 4; ++j)
        acc[i][j] = __builtin_amdgcn_mfma_f32_16x16x32_bf16(af2[i], bfj[j], acc[i][j], 0, 0, 0);
  }

  // packed epilogue: idx = ((kb*16+h)*16+t)*1024 + half*512 + g*128 + r16*8 + e
  #pragma unroll
  for (int i = 0; i < 8; ++i)
    #pragma unroll
    for (int j = 0; j < 4; ++j)
      #pragma unroll
      for (int rg = 0; rg < 4; ++rg) {
        size_t row = m0 + (wr << 7) + (i << 4) + (g << 2) + rg;
        size_t col = n0 + (wc << 6) + (j << 4) + rr;
        int kb = (int)(row >> 8), t = (int)((row >> 4) & 15), r16 = (int)(row & 15);
        int h = (int)(col >> 6), ch = (int)(col & 63);
        size_t idx = ((((size_t)kb * 16 + h) * 16 + t) << 10)
                   + ((ch >> 5) << 9) + (((ch >> 3) & 3) << 7) + (r16 << 3) + (ch & 7);
        Cpk[idx] = f2bf(acc[i][j][rg]);
      }

  // ---------------- Q-projection coda: 64 blocks, one tile PER WAVE ----------------
  if ((wg & 63) < 8) {
    const int ti = ((wg >> 6) << 6) + ((wg & 7) << 3) + wid;   // 0..511
    const int mq = ti >> 6, nq = ti & 63;
    const ushort_t* qa = qA + (size_t)(mq * 16 + rr) * 1024 + g * 8;
    const ushort_t* qb = qB + (size_t)(nq * 16 + rr) * 1024 + g * 8;
    f32x4 qacc0 = (f32x4){0.f, 0.f, 0.f, 0.f};
    f32x4 qacc1 = (f32x4){0.f, 0.f, 0.f, 0.f};
    #pragma unroll
    for (int kk = 0; kk < 32; kk += 2) {
      bf16x8 a0 = *(const bf16x8*)(qa + kk * 32);
      bf16x8 b0 = *(const bf16x8*)(qb + kk * 32);
      bf16x8 a1 = *(const bf16x8*)(qa + kk * 32 + 32);
      bf16x8 b1 = *(const bf16x8*)(qb + kk * 32 + 32);
      qacc0 = __builtin_amdgcn_mfma_f32_16x16x32_bf16(a0, b0, qacc0, 0, 0, 0);
      qacc1 = __builtin_amdgcn_mfma_f32_16x16x32_bf16(a1, b1, qacc1, 0, 0, 0);
    }
    #pragma unroll
    for (int rg = 0; rg < 4; ++rg)
      qC[(size_t)(mq * 16 + (g << 2) + rg) * 1024 + nq * 16 + rr] = f2bf(qacc0[rg] + qacc1[rg]);
  }
}

// ---------------------------------------------------------------------------
// K4a: scores kernel (unchanged: packed K loads, static indexing).
// ---------------------------------------------------------------------------
__global__ __launch_bounds__(256, 3) void scores_kernel(const ushort_t* __restrict__ qp,   // [128][1024]
                                                        const ushort_t* __restrict__ kpk,  // packed
                                                        ushort_t* __restrict__ wbuf) {     // [128][128][256]
  __shared__ float pbuf[2][16][258];

  const int tid = threadIdx.x, lane = tid & 63, wid = tid >> 6;
  const int g = lane >> 4, rr = lane & 15;

  const int b = blockIdx.x;
  const int wg = (b & 7) * 128 + (b >> 3);
  const int kb = wg >> 3;
  const int q0 = (wg & 7) << 4;

  const int hs = wid;

  float w_acc[16][4];
  #pragma unroll
  for (int t = 0; t < 16; ++t)
    #pragma unroll
    for (int r = 0; r < 4; ++r) w_acc[t][r] = 0.f;

  const ushort_t* qrow = qp + (size_t)(q0 + rr) * 1024;
  const ushort_t* kbb  = kpk + ((size_t)kb * 16) * 16384 + g * 128 + rr * 8;

  for (int hp = 0; hp < 4; ++hp) {
    const int h = hp * 4 + hs;
    const int co = h * 64 + g * 8;
    bf16x8 aq0 = *(const bf16x8*)(qrow + co);
    bf16x8 aq1 = *(const bf16x8*)(qrow + co + 32);
    const ushort_t* hb = kbb + (size_t)h * 16384;
    f32x4 s[16];
    #pragma unroll
    for (int t = 0; t < 16; ++t) {
      bf16x8 b0 = *(const bf16x8*)(hb + t * 1024);
      bf16x8 b1 = *(const bf16x8*)(hb + t * 1024 + 512);
      f32x4 a = (f32x4){0.f, 0.f, 0.f, 0.f};
      a = __builtin_amdgcn_mfma_f32_16x16x32_bf16(aq0, b0, a, 0, 0, 0);
      a = __builtin_amdgcn_mfma_f32_16x16x32_bf16(aq1, b1, a, 0, 0, 0);
      s[t] = a;
    }
    #pragma unroll
    for (int r = 0; r < 4; ++r) {
      float mx = s[0][r];
      #pragma unroll
      for (int t = 1; t < 16; ++t) mx = fmaxf(mx, s[t][r]);
      mx = fmaxf(mx, __shfl_xor(mx, 1));
      mx = fmaxf(mx, __shfl_xor(mx, 2));
      mx = fmaxf(mx, __shfl_xor(mx, 4));
      mx = fmaxf(mx, __shfl_xor(mx, 8));
      float sum = 0.f;
      float e[16];
      #pragma unroll
      for (int t = 0; t < 16; ++t) {
        e[t] = __expf((s[t][r] - mx) * 0.125f);
        sum += e[t];
      }
      sum += __shfl_xor(sum, 1);
      sum += __shfl_xor(sum, 2);
      sum += __shfl_xor(sum, 4);
      sum += __shfl_xor(sum, 8);
      float inv = 1.0f / sum;
      #pragma unroll
      for (int t = 0; t < 16; ++t) w_acc[t][r] += e[t] * inv;
    }
  }

  __syncthreads();
  if (hs >= 2) {
    #pragma unroll
    for (int t = 0; t < 16; ++t)
      #pragma unroll
      for (int r = 0; r < 4; ++r)
        pbuf[hs - 2][(g << 2) + r][t * 16 + rr] = w_acc[t][r];
  }
  __syncthreads();
  if (hs < 2) {
    #pragma unroll
    for (int t = 0; t < 16; ++t)
      #pragma unroll
      for (int r = 0; r < 4; ++r)
        w_acc[t][r] += pbuf[hs][(g << 2) + r][t * 16 + rr];
    if (hs == 1) {
      #pragma unroll
      for (int t = 0; t < 16; ++t)
        #pragma unroll
        for (int r = 0; r < 4; ++r)
          pbuf[1][(g << 2) + r][t * 16 + rr] = w_acc[t][r];
    }
  }
  __syncthreads();
  if (hs == 0) {
    ushort_t* wb = wbuf + (size_t)kb * 32768;
    #pragma unroll
    for (int t = 0; t < 16; ++t)
      #pragma unroll
      for (int r = 0; r < 4; ++r) {
        float v = w_acc[t][r] + pbuf[1][(g << 2) + r][t * 16 + rr];
        wb[(size_t)(q0 + (g << 2) + r) * 256 + t * 16 + rr] = f2bf(v);
      }
  }
}

// ---------------------------------------------------------------------------
// K4b: PV kernel (unchanged).
// ---------------------------------------------------------------------------
__global__ __launch_bounds__(256, 4) void pv_kernel(const ushort_t* __restrict__ wbuf, // [128][128][256]
                                                    const float* __restrict__ kx,      // [32768][1024]
                                                    float* __restrict__ xout) {        // [128][128][1024]
  const int tid = threadIdx.x, lane = tid & 63, wid = tid >> 6;
  const int g = lane >> 4, rr = lane & 15;

  const int b = blockIdx.x;
  const int wg = (b & 7) * 128 + (b >> 3);
  const int kb = wg >> 3;
  const int c0 = (wg & 7) * 128;

  const int wr = wid >> 1, wc = wid & 1;

  f32x4 acc[4][4];
  #pragma unroll
  for (int i = 0; i < 4; ++i)
    #pragma unroll
    for (int j = 0; j < 4; ++j) acc[i][j] = (f32x4){0.f, 0.f, 0.f, 0.f};

  const ushort_t* wb = wbuf + (size_t)kb * 32768;
  const float* kxb = kx + (size_t)kb * 256 * 1024;

  for (int nc = 0; nc < 8; ++nc) {
    const int n0 = nc * 32 + g * 8;
    bf16x8 af[4];
    #pragma unroll
    for (int i = 0; i < 4; ++i) {
      int q = (wr << 6) + (i << 4) + rr;
      af[i] = *(const bf16x8*)(wb + (size_t)q * 256 + n0);
    }
    #pragma unroll
    for (int j = 0; j < 4; ++j) {
      int c = c0 + (wc << 6) + (j << 4) + rr;
      const float* src = kxb + (size_t)n0 * 1024 + c;
      float f[8];
      #pragma unroll
      for (int jj = 0; jj < 8; ++jj) f[jj] = src[(size_t)jj * 1024];
      bf16x8 bb;
      #pragma unroll
      for (int jj = 0; jj < 8; ++jj) bb[jj] = (__bf16)f[jj];
      #pragma unroll
      for (int i = 0; i < 4; ++i)
        acc[i][j] = __builtin_amdgcn_mfma_f32_16x16x32_bf16(af[i], bb, acc[i][j], 0, 0, 0);
    }
  }

  #pragma unroll
  for (int i = 0; i < 4; ++i)
    #pragma unroll
    for (int j = 0; j < 4; ++j)
      #pragma unroll
      for (int rg = 0; rg < 4; ++rg) {
        int q = (wr << 6) + (i << 4) + (g << 2) + rg;
        int c = c0 + (wc << 6) + (j << 4) + rr;
        xout[((size_t)q * 128 + kb) * 1024 + c] = acc[i][j][rg];
      }
}

// ---------------------------------------------------------------------------
// launcher
// ---------------------------------------------------------------------------
extern "C" void kernel_launch(void* const* d_in, const int* in_sizes, int n_in,
                              void* d_out, int out_size, void* d_ws, size_t ws_size,
                              hipStream_t stream) {
  const float* qx = (const float*)d_in[0];
  const float* kx = (const float*)d_in[1];
  const float* gq = (const float*)d_in[2];
  const float* bq = (const float*)d_in[3];
  const float* gk = (const float*)d_in[4];
  const float* bk = (const float*)d_in[5];
  const float* Wq = (const float*)d_in[6];
  const float* Wk = (const float*)d_in[7];

  char* ws = (char*)d_ws;
  // ws layout (total 72.25 MiB):
  //   [0, 64M)            kkp   : PACKED K-projection bf16 (live: gemm256 -> scores)
  //   [64M, 64M+256K)     qproj : Q-projection bf16 [128][1024]    (live: gemm256 -> scores)
  //   [64M+256K, +8M)     wbuf  : head-summed weights bf16 [128][128][256] (live: scores -> pv)
  //     aliased inside wbuf (dead before scores runs):
  //       qln  @wbuf+0     [128][1024] bf16   (live: ln -> gemm256)
  //       Wqb  @wbuf+256K  [1024][1024] bf16  (live: cvt -> gemm256)
  //       Wkb  @wbuf+2.25M [1024][1024] bf16  (live: cvt -> gemm256)
  ushort_t* kkp   = (ushort_t*)(ws);
  ushort_t* qproj = (ushort_t*)(ws + 67108864);
  ushort_t* wbuf  = (ushort_t*)(ws + 67371008);
  ushort_t* qln   = (ushort_t*)(ws + 67371008);
  ushort_t* Wqb   = (ushort_t*)(ws + 67371008 + 262144);
  ushort_t* Wkb   = (ushort_t*)(ws + 67371008 + 2359296);
  // kln (bf16, 64 MiB) lives in d_out; dead after gemm256, overwritten by pv.
  ushort_t* kln  = (ushort_t*)d_out;
  float*    xout = (float*)d_out;

  cvt_bf16_kernel<<<1024, 256, 0, stream>>>(Wq, Wqb, 262144);
  cvt_bf16_kernel<<<1024, 256, 0, stream>>>(Wk, Wkb, 262144);
  ln_kernel<<<32896, 256, 0, stream>>>(kx, qx, gk, bk, gq, bq, kln, qln);
  gemm256_kernel<<<512, 512, 0, stream>>>(kln, Wkb, kkp, qln, Wqb, qproj, 32768, 1024);
  scores_kernel<<<1024, 256, 0, stream>>>(qproj, kkp, wbuf);
  pv_kernel<<<1024, 256, 0, stream>>>(wbuf, kx, xout);
}